// Round 2
// baseline (1166.482 us; speedup 1.0000x reference)
//
#include <hip/hip_runtime.h>

#define DD 128
#define KSPLIT 4
#define RT 32   // selected rows per block (K2)
#define KT 64   // k-chunk (K2)

typedef float f4 __attribute__((ext_vector_type(4)));

// ---------------- K1: LayerNorm + gumbel gate + compaction ----------------
__global__ __launch_bounds__(256) void k1_ln_gate(
    const float* __restrict__ x, const float* __restrict__ u,
    const float* __restrict__ Wn, const float* __restrict__ bn,
    const float* __restrict__ g_in, const float* __restrict__ b_in,
    float* __restrict__ x_norm, float* __restrict__ gatef,
    int* __restrict__ rows_sel, int* __restrict__ cnt, int N) {
  int wave = threadIdx.x >> 6, lane = threadIdx.x & 63;
  int row = blockIdx.x * 4 + wave;
  if (row >= N) return;
  int d0 = lane, d1 = lane + 64;
  float x0 = x[(size_t)row * DD + d0];
  float x1 = x[(size_t)row * DD + d1];
  float s = x0 + x1;
#pragma unroll
  for (int off = 32; off; off >>= 1) s += __shfl_xor(s, off, 64);
  float mean = s * (1.0f / 128.0f);
  float dx0 = x0 - mean, dx1 = x1 - mean;
  float v = dx0 * dx0 + dx1 * dx1;
#pragma unroll
  for (int off = 32; off; off >>= 1) v += __shfl_xor(v, off, 64);
  float inv = 1.0f / sqrtf(v * (1.0f / 128.0f) + 1e-5f);
  float xn0 = dx0 * inv * g_in[d0] + b_in[d0];
  float xn1 = dx1 * inv * g_in[d1] + b_in[d1];
  x_norm[(size_t)row * DD + d0] = xn0;
  x_norm[(size_t)row * DD + d1] = xn1;
  // logits = x_norm @ Wn  (Wn is (128,2) row-major)
  float l0 = xn0 * Wn[2 * d0] + xn1 * Wn[2 * d1];
  float l1 = xn0 * Wn[2 * d0 + 1] + xn1 * Wn[2 * d1 + 1];
#pragma unroll
  for (int off = 32; off; off >>= 1) {
    l0 += __shfl_xor(l0, off, 64);
    l1 += __shfl_xor(l1, off, 64);
  }
  float u0 = u[2 * row], u1 = u[2 * row + 1];
  float g0 = -logf(-logf(fminf(fmaxf(u0, 1e-10f), 1.0f)) + 1e-10f);
  float g1 = -logf(-logf(fminf(fmaxf(u1, 1e-10f), 1.0f)) + 1e-10f);
  float z0 = l0 + bn[0] + g0;
  float z1 = l1 + bn[1] + g1;
  bool gate = (z1 > z0);  // argmax ties -> index 0 -> gate 0
  if (lane == 0) {
    gatef[row] = gate ? 1.0f : 0.0f;
    if (gate) {
      int p = atomicAdd(cnt, 1);
      rows_sel[p] = row;
    }
  }
}

// ---------------- K2: view2 = adj @ (gate*x_norm), fp32 VALU, LDS-tiled, split-K atomics ----
__global__ __launch_bounds__(256) void k2_fp32(
    const float* __restrict__ adj, const float* __restrict__ x_norm,
    const float* __restrict__ gatef, const int* __restrict__ rows_sel,
    const int* __restrict__ cnt, float* __restrict__ view2, int N) {
  __shared__ float xs[KT][DD];   // 32 KB: gated x_norm tile [k][d]
  __shared__ float ast[KT][RT];  // 8 KB: adj tile transposed [k][r]
  __shared__ int rloc[RT];
  const int Nc = *cnt;
  const int rbase = blockIdx.x * RT;
  if (rbase >= Nc) return;
  const int tid = threadIdx.x;
  if (tid < RT) {
    int m = rbase + tid;
    rloc[tid] = rows_sel[m < Nc ? m : Nc - 1];
  }
  __syncthreads();

  const int wave = tid >> 6, lane = tid & 63;
  const int c0 = (lane & 31) * 4;             // 4 output cols
  const int r0 = wave * 8 + (lane >> 5) * 4;  // 4 output rows (local)

  f4 acc0 = {0.f, 0.f, 0.f, 0.f};
  f4 acc1 = acc0, acc2 = acc0, acc3 = acc0;

  const int kbeg = blockIdx.y * (N / KSPLIT);
  const int kend = kbeg + N / KSPLIT;

  for (int k0 = kbeg; k0 < kend; k0 += KT) {
    __syncthreads();
    // stage gated x_norm tile [KT][128]
    for (int i = tid; i < KT * 32; i += 256) {
      int kr = i >> 5, c = (i & 31) << 2;
      f4 v = *(const f4*)(x_norm + (size_t)(k0 + kr) * DD + c);
      float g = gatef[k0 + kr];
      *(f4*)&xs[kr][c] = v * g;
    }
    // stage adj tile transposed [KT][RT]
    for (int i = tid; i < RT * (KT / 4); i += 256) {
      int r = i >> 4, c4 = (i & 15) << 2;
      f4 a = *(const f4*)(adj + (size_t)rloc[r] * N + k0 + c4);
      ast[c4 + 0][r] = a[0];
      ast[c4 + 1][r] = a[1];
      ast[c4 + 2][r] = a[2];
      ast[c4 + 3][r] = a[3];
    }
    __syncthreads();
#pragma unroll 8
    for (int kk = 0; kk < KT; ++kk) {
      f4 xv = *(const f4*)&xs[kk][c0];
      f4 av = *(const f4*)&ast[kk][r0];
      acc0 += av[0] * xv;
      acc1 += av[1] * xv;
      acc2 += av[2] * xv;
      acc3 += av[3] * xv;
    }
  }

  const int mbase = rbase + r0;
  f4 accs[4] = {acc0, acc1, acc2, acc3};
#pragma unroll
  for (int ri = 0; ri < 4; ++ri) {
    int m = mbase + ri;
    if (m < Nc) {
      float* o = view2 + (size_t)rloc[r0 + ri] * DD + c0;
      atomicAdd(o + 0, accs[ri][0]);
      atomicAdd(o + 1, accs[ri][1]);
      atomicAdd(o + 2, accs[ri][2]);
      atomicAdd(o + 3, accs[ri][3]);
    }
  }
}

// ---------------- K3: fusion gate + mix + residual LayerNorm (two-pass var) ----------------
#define K3R 8
__global__ __launch_bounds__(256) void k3_epilogue(
    const float* __restrict__ x, const float* __restrict__ x_norm,
    const float* __restrict__ view2,
    const float* __restrict__ W1, const float* __restrict__ b1,
    const float* __restrict__ W2, const float* __restrict__ b2,
    const float* __restrict__ Wg, const float* __restrict__ bg,
    const float* __restrict__ g_out, const float* __restrict__ b_out,
    float* __restrict__ out, int N) {
  __shared__ float t1[K3R][DD];
  __shared__ float t2[K3R][DD];
  const int row0 = blockIdx.x * K3R;
  const int tid = threadIdx.x;
  for (int idx = tid; idx < K3R * DD; idx += 256) {
    int r = idx >> 7, j = idx & 127;
    t1[r][j] = x_norm[(size_t)(row0 + r) * DD + j];
    t2[r][j] = view2[(size_t)(row0 + r) * DD + j];
  }
  __syncthreads();
  const int r = tid >> 5;         // 0..7
  const int kb = (tid & 31) * 4;  // column base 0..124
  f4 fg4 = {0.f, 0.f, 0.f, 0.f}, h14 = fg4, h24 = fg4;
#pragma unroll 4
  for (int j = 0; j < DD; ++j) {
    float tv1 = t1[r][j];
    float tv2 = t2[r][j];
    f4 wg1 = *(const f4*)(Wg + j * DD + kb);
    f4 wg2 = *(const f4*)(Wg + (j + DD) * DD + kb);
    f4 w1 = *(const f4*)(W1 + j * DD + kb);
    f4 w2 = *(const f4*)(W2 + j * DD + kb);
    fg4 += tv1 * wg1 + tv2 * wg2;
    h14 += tv1 * w1;
    h24 += tv2 * w2;
  }
  f4 bgv = *(const f4*)(bg + kb);
  f4 b1v = *(const f4*)(b1 + kb);
  f4 b2v = *(const f4*)(b2 + kb);
  f4 fg;
#pragma unroll
  for (int c = 0; c < 4; ++c) fg[c] = 1.0f / (1.0f + expf(-(fg4[c] + bgv[c])));
  f4 h1 = h14 + b1v;
  f4 h2 = h24 + b2v;
  f4 fused = fg * h1 + (1.0f - fg) * h2;
  f4 xres = *(const f4*)(x + (size_t)(row0 + r) * DD + kb);
  f4 sres = fused + xres;
  // two-pass LN to match reference formula exactly
  float ps = sres[0] + sres[1] + sres[2] + sres[3];
#pragma unroll
  for (int off = 16; off; off >>= 1) ps += __shfl_xor(ps, off, 32);
  float mean = ps * (1.0f / 128.0f);
  f4 dx = sres - mean;
  float pq = dx[0] * dx[0] + dx[1] * dx[1] + dx[2] * dx[2] + dx[3] * dx[3];
#pragma unroll
  for (int off = 16; off; off >>= 1) pq += __shfl_xor(pq, off, 32);
  float var = pq * (1.0f / 128.0f);
  float inv = 1.0f / sqrtf(var + 1e-5f);
  f4 gout = *(const f4*)(g_out + kb);
  f4 bout = *(const f4*)(b_out + kb);
  f4 o = dx * inv * gout + bout;
  *(f4*)(out + (size_t)(row0 + r) * DD + kb) = o;
}

extern "C" void kernel_launch(void* const* d_in, const int* in_sizes, int n_in,
                              void* d_out, int out_size, void* d_ws, size_t ws_size,
                              hipStream_t stream) {
  const float* x = (const float*)d_in[0];
  const float* adj = (const float*)d_in[1];
  const float* u = (const float*)d_in[2];
  const float* W1 = (const float*)d_in[3];
  const float* b1 = (const float*)d_in[4];
  const float* W2 = (const float*)d_in[5];
  const float* b2 = (const float*)d_in[6];
  const float* Wg = (const float*)d_in[7];
  const float* bg = (const float*)d_in[8];
  const float* Wn = (const float*)d_in[9];
  const float* bn = (const float*)d_in[10];
  const float* g_in = (const float*)d_in[11];
  const float* b_in = (const float*)d_in[12];
  const float* g_out = (const float*)d_in[13];
  const float* b_out = (const float*)d_in[14];
  float* out = (float*)d_out;

  const int N = in_sizes[2] / 2;  // 12288

  char* ws = (char*)d_ws;
  int* cnt = (int*)ws;                          // 4 B (pad to 256)
  int* rows_sel = (int*)(ws + 256);             // N*4
  size_t o_gate = 256 + (size_t)N * 4;
  float* gatef = (float*)(ws + o_gate);         // N*4
  size_t o_xn = o_gate + (size_t)N * 4;
  float* x_norm = (float*)(ws + o_xn);          // N*128*4
  size_t o_v2 = o_xn + (size_t)N * DD * 4;
  float* view2 = (float*)(ws + o_v2);           // N*128*4
  // total ~12.7 MB

  hipMemsetAsync(cnt, 0, 4, stream);
  hipMemsetAsync(view2, 0, (size_t)N * DD * 4, stream);

  k1_ln_gate<<<N / 4, 256, 0, stream>>>(x, u, Wn, bn, g_in, b_in, x_norm, gatef,
                                        rows_sel, cnt, N);
  k2_fp32<<<dim3(N / RT, KSPLIT), 256, 0, stream>>>(adj, x_norm, gatef, rows_sel,
                                                    cnt, view2, N);
  k3_epilogue<<<N / K3R, 256, 0, stream>>>(x, x_norm, view2, W1, b1, W2, b2, Wg,
                                           bg, g_out, b_out, out, N);
}